// Round 1
// baseline (7673.859 us; speedup 1.0000x reference)
//
#include <hip/hip_runtime.h>
#include <stdint.h>

// Problem constants (from setup_inputs): B=2048, D_ACT=2048, D_DICT=32768, K=64
#define B_ROWS 2048
#define DACT   2048
#define DDICT  32768
#define NTOT   (67108864UL)   // B_ROWS * DDICT

// ---------------- GEMM: acts = relu((x - b_dec) @ W^T + b_enc), f64 accumulate ----------------
// Tile 64x64, BK=32, 16x16 threads, 4x4 outputs/thread, f64 accumulators.
#define BM 64
#define BN 64
#define BKK 32
#define TM 4
#define TN 4

__global__ __launch_bounds__(256) void gemm_kernel(
    const float* __restrict__ x, const float* __restrict__ W,
    const float* __restrict__ b_enc, const float* __restrict__ b_dec,
    float* __restrict__ out)
{
    __shared__ float As[BM][BKK + 1];   // +1 pad: conflict-free column reads
    __shared__ float Bs[BN][BKK + 1];

    const int tid = threadIdx.x;
    const int tx = tid & 15;            // n direction
    const int ty = tid >> 4;            // m direction
    const int m0 = blockIdx.y * BM;
    const int n0 = blockIdx.x * BN;

    double acc[TM][TN];
#pragma unroll
    for (int i = 0; i < TM; i++)
#pragma unroll
        for (int j = 0; j < TN; j++) acc[i][j] = 0.0;

    for (int k0 = 0; k0 < DACT; k0 += BKK) {
        // stage A (x - b_dec): 64x32 floats = 512 float4, 2 per thread
#pragma unroll
        for (int v = tid; v < BM * BKK / 4; v += 256) {
            int r = v >> 3;
            int c4 = v & 7;
            const float4 xv = *reinterpret_cast<const float4*>(&x[(size_t)(m0 + r) * DACT + k0 + c4 * 4]);
            const float4 bd = *reinterpret_cast<const float4*>(&b_dec[k0 + c4 * 4]);
            As[r][c4 * 4 + 0] = xv.x - bd.x;
            As[r][c4 * 4 + 1] = xv.y - bd.y;
            As[r][c4 * 4 + 2] = xv.z - bd.z;
            As[r][c4 * 4 + 3] = xv.w - bd.w;
        }
        // stage B (W rows)
#pragma unroll
        for (int v = tid; v < BN * BKK / 4; v += 256) {
            int r = v >> 3;
            int c4 = v & 7;
            const float4 wv = *reinterpret_cast<const float4*>(&W[(size_t)(n0 + r) * DACT + k0 + c4 * 4]);
            Bs[r][c4 * 4 + 0] = wv.x;
            Bs[r][c4 * 4 + 1] = wv.y;
            Bs[r][c4 * 4 + 2] = wv.z;
            Bs[r][c4 * 4 + 3] = wv.w;
        }
        __syncthreads();
#pragma unroll
        for (int kk = 0; kk < BKK; ++kk) {
            float a[TM], b[TN];
#pragma unroll
            for (int i = 0; i < TM; i++) a[i] = As[ty * TM + i][kk];
#pragma unroll
            for (int j = 0; j < TN; j++) b[j] = Bs[tx * TN + j][kk];
#pragma unroll
            for (int i = 0; i < TM; i++)
#pragma unroll
                for (int j = 0; j < TN; j++)
                    acc[i][j] = fma((double)a[i], (double)b[j], acc[i][j]);
        }
        __syncthreads();
    }

#pragma unroll
    for (int i = 0; i < TM; i++) {
        int m = m0 + ty * TM + i;
#pragma unroll
        for (int j = 0; j < TN; j++) {
            int n = n0 + tx * TN + j;
            double v = acc[i][j] + (double)b_enc[n];
            float f = (float)v;
            // relu; guard -0.0 (bit pattern 0x80000000 would break uint ordering)
            f = (f > 0.0f) ? f : 0.0f;
            out[(size_t)m * DDICT + n] = f;
        }
    }
}

// ---------------- radix-select passes on positive-float bit patterns ----------------
// Pass layout: bits[31:21] (11b) -> bits[20:10] (11b) -> bits[9:0] (10b)

__global__ __launch_bounds__(256) void hist_kernel(
    const float* __restrict__ acts, uint32_t* __restrict__ hist,
    const uint32_t* __restrict__ prefix_ptr, int prefix_shift,
    int bucket_shift, uint32_t mask, int nbuckets)
{
    __shared__ uint32_t h[2048];
    for (int i = threadIdx.x; i < nbuckets; i += blockDim.x) h[i] = 0;
    __syncthreads();
    const uint32_t pref = prefix_ptr ? *prefix_ptr : 0;
    const bool has_pref = (prefix_ptr != nullptr);
    const size_t stride = (size_t)gridDim.x * blockDim.x;
    for (size_t i = (size_t)blockIdx.x * blockDim.x + threadIdx.x; i < NTOT; i += stride) {
        uint32_t bits = __float_as_uint(acts[i]);
        if (has_pref && (bits >> prefix_shift) != pref) continue;
        atomicAdd(&h[(bits >> bucket_shift) & mask], 1u);
    }
    __syncthreads();
    for (int i = threadIdx.x; i < nbuckets; i += blockDim.x)
        if (h[i]) atomicAdd(&hist[i], h[i]);
}

// single-wave scan: find cutoff bucket from the top. state layout:
// [0]=b0 prefix11, [1]=rem1, [2]=prefix22, [3]=rem2, [4]=T bits, [5]=t_inc, [6]=cnt_eq
__global__ void scan_kernel(const uint32_t* __restrict__ hist, int nbuckets,
                            const int* __restrict__ kptr, uint32_t* __restrict__ state, int mode)
{
    const int lane = threadIdx.x;   // exactly 64 threads
    uint32_t rem;
    if (mode == 0)      rem = (uint32_t)(*kptr) * (uint32_t)B_ROWS;
    else if (mode == 1) rem = state[1];
    else                rem = state[3];

    const int seg = nbuckets >> 6;
    const int base = lane * seg;
    uint32_t s = 0;
    for (int j = 0; j < seg; ++j) s += hist[base + j];

    // inclusive suffix sum across lanes
    uint32_t suf = s;
    for (int off = 1; off < 64; off <<= 1) {
        uint32_t o = __shfl_down(suf, off);
        if (lane + off < 64) suf += o;
    }
    uint32_t snext = __shfl_down(suf, 1);
    if (lane == 63) snext = 0;

    if (suf >= rem && snext < rem) {
        uint32_t cum = snext;           // count strictly above this segment
        int bstar = base;
        for (int b = base + seg - 1; b >= base; --b) {
            cum += hist[b];
            if (cum >= rem) { bstar = b; break; }
        }
        uint32_t greater = cum - hist[bstar];  // count strictly above bucket bstar
        uint32_t inner = rem - greater;        // how many to take from bucket bstar (>=1)
        if (mode == 0)      { state[0] = (uint32_t)bstar; state[1] = inner; }
        else if (mode == 1) { state[2] = (state[0] << 11) | (uint32_t)bstar; state[3] = inner; }
        else { state[4] = (state[2] << 10) | (uint32_t)bstar; state[5] = inner; state[6] = hist[bstar]; }
    }
}

// collect flat indices of elements whose bits == T (the cutoff value)
__global__ __launch_bounds__(256) void gather_eq(
    const float* __restrict__ acts, const uint32_t* __restrict__ state,
    uint32_t* __restrict__ eq_cnt, uint32_t* __restrict__ eq_idx)
{
    const uint32_t T = state[4];
    const size_t stride = (size_t)gridDim.x * blockDim.x;
    for (size_t i = (size_t)blockIdx.x * blockDim.x + threadIdx.x; i < NTOT; i += stride) {
        if (__float_as_uint(acts[i]) == T) {
            uint32_t p = atomicAdd(eq_cnt, 1u);
            if (p < 1024u) eq_idx[p] = (uint32_t)i;
        }
    }
}

// recompute exact f64 activation for each tied element (breaks within-f32-ulp ties)
__global__ __launch_bounds__(256) void eqval_kernel(
    const float* __restrict__ x, const float* __restrict__ W,
    const float* __restrict__ b_enc, const float* __restrict__ b_dec,
    const uint32_t* __restrict__ eq_cnt, const uint32_t* __restrict__ eq_idx,
    double* __restrict__ eq_val)
{
    __shared__ double red[256];
    uint32_t n = *eq_cnt; if (n > 1024u) n = 1024u;
    if (blockIdx.x >= n) return;
    const uint32_t idx = eq_idx[blockIdx.x];
    const int brow = (int)(idx >> 15);         // DDICT = 2^15
    const int f = (int)(idx & 32767u);
    double s = 0.0;
    for (int d = threadIdx.x; d < DACT; d += 256)
        s = fma((double)x[(size_t)brow * DACT + d] - (double)b_dec[d],
                (double)W[(size_t)f * DACT + d], s);
    red[threadIdx.x] = s;
    __syncthreads();
    for (int off = 128; off > 0; off >>= 1) {
        if (threadIdx.x < off) red[threadIdx.x] += red[threadIdx.x + off];
        __syncthreads();
    }
    if (threadIdx.x == 0) eq_val[blockIdx.x] = red[0] + (double)b_enc[f];
}

// zero everything strictly below the cutoff value
__global__ __launch_bounds__(256) void finalize_kernel(
    float* __restrict__ out, const uint32_t* __restrict__ state)
{
    const uint32_t T = state[4];
    const size_t stride = (size_t)gridDim.x * blockDim.x;
    for (size_t i = (size_t)blockIdx.x * blockDim.x + threadIdx.x; i < NTOT; i += stride) {
        if (__float_as_uint(out[i]) < T) out[i] = 0.0f;
    }
}

// among tied elements (==T), keep only the t_inc best by (f64 value desc, index asc)
__global__ void fixup_kernel(float* __restrict__ out, const uint32_t* __restrict__ state,
                             const uint32_t* __restrict__ eq_cnt,
                             const uint32_t* __restrict__ eq_idx,
                             const double* __restrict__ eq_val)
{
    uint32_t n = *eq_cnt; if (n > 1024u) n = 1024u;
    const uint32_t t_inc = state[5];
    for (uint32_t i = threadIdx.x; i < n; i += blockDim.x) {
        const double v = eq_val[i];
        const uint32_t idx = eq_idx[i];
        uint32_t rank = 0;
        for (uint32_t j = 0; j < n; ++j) {
            if (eq_val[j] > v || (eq_val[j] == v && eq_idx[j] < idx)) rank++;
        }
        if (rank >= t_inc) out[idx] = 0.0f;
    }
}

extern "C" void kernel_launch(void* const* d_in, const int* in_sizes, int n_in,
                              void* d_out, int out_size, void* d_ws, size_t ws_size,
                              hipStream_t stream)
{
    const float* x     = (const float*)d_in[0];
    const float* W     = (const float*)d_in[1];
    const float* b_enc = (const float*)d_in[2];
    const float* b_dec = (const float*)d_in[3];
    const int*   kp    = (const int*)d_in[4];
    float* out = (float*)d_out;

    // workspace layout (u32 offsets)
    uint32_t* ws     = (uint32_t*)d_ws;
    uint32_t* hist0  = ws;            // 2048
    uint32_t* hist1  = ws + 2048;     // 2048
    uint32_t* hist2  = ws + 4096;     // 1024
    uint32_t* state  = ws + 6144;     // 16
    uint32_t* eq_cnt = ws + 6160;     // 1 (+pad)
    uint32_t* eq_idx = ws + 6176;     // 1024
    double*   eq_val = (double*)(ws + 7200);  // 1024 doubles, 8B-aligned offset

    // zero the counter region (ws is re-poisoned to 0xAA before every launch)
    hipMemsetAsync(d_ws, 0, (size_t)(7200 + 2048) * sizeof(uint32_t), stream);

    gemm_kernel<<<dim3(DDICT / BN, B_ROWS / BM), 256, 0, stream>>>(x, W, b_enc, b_dec, out);

    hist_kernel<<<4096, 256, 0, stream>>>(out, hist0, nullptr, 0, 21, 0x7FFu, 2048);
    scan_kernel<<<1, 64, 0, stream>>>(hist0, 2048, kp, state, 0);
    hist_kernel<<<4096, 256, 0, stream>>>(out, hist1, state + 0, 21, 10, 0x7FFu, 2048);
    scan_kernel<<<1, 64, 0, stream>>>(hist1, 2048, kp, state, 1);
    hist_kernel<<<4096, 256, 0, stream>>>(out, hist2, state + 2, 10, 0, 0x3FFu, 1024);
    scan_kernel<<<1, 64, 0, stream>>>(hist2, 1024, kp, state, 2);

    gather_eq<<<4096, 256, 0, stream>>>(out, state, eq_cnt, eq_idx);
    eqval_kernel<<<1024, 256, 0, stream>>>(x, W, b_enc, b_dec, eq_cnt, eq_idx, eq_val);
    finalize_kernel<<<4096, 256, 0, stream>>>(out, state);
    fixup_kernel<<<1, 256, 0, stream>>>(out, state, eq_cnt, eq_idx, eq_val);
}

// Round 4
// 1990.377 us; speedup vs baseline: 3.8555x; 3.8555x over previous
//
#include <hip/hip_runtime.h>
#include <stdint.h>

// Problem constants: B=2048, D_ACT=2048, D_DICT=32768, K=64
#define B_ROWS 2048
#define DACT   2048
#define DDICT  32768
#define NTOT   67108864UL   // B_ROWS * DDICT
#define BM 128
#define BN 128
#define BK 32
#define CAP 8192            // band capacity (expected ~1.9k)
#define BETA 2e-3f          // band half-width; worst-case |approx-exact| <= ~6e-4

using f4    = __attribute__((ext_vector_type(4))) float;
using f32x4 = __attribute__((ext_vector_type(4))) float;
using frag  = __attribute__((ext_vector_type(8))) short;   // 8 x bf16
using us4   = __attribute__((ext_vector_type(4))) unsigned short;

__device__ __forceinline__ unsigned short f2bf(float f) {
    unsigned u = __float_as_uint(f);
    u += 0x7FFFu + ((u >> 16) & 1u);     // RNE
    return (unsigned short)(u >> 16);
}
__device__ __forceinline__ float bf2f(unsigned short h) {
    return __uint_as_float(((unsigned)h) << 16);
}

// ---------------- bf16-split MFMA GEMM: out = relu((x-b_dec) @ W^T + b_enc) ----------------
// 3-class split: A1B1 + A1B2 + A2B1 chained into one f32 accumulator.
// |error| <= ~6e-4 worst-case; selection corrected exactly by the band fixup below.
__global__ __launch_bounds__(256) void gemm_kernel(
    const float* __restrict__ x, const float* __restrict__ W,
    const float* __restrict__ b_enc, const float* __restrict__ b_dec,
    float* __restrict__ out)
{
    __shared__ __align__(16) unsigned short lds[4 * BM * BK];  // A1,A2,B1,B2 planes
    unsigned short* sA1 = lds;
    unsigned short* sA2 = lds + BM * BK;
    unsigned short* sB1 = lds + 2 * BM * BK;
    unsigned short* sB2 = lds + 3 * BM * BK;

    const int tid = threadIdx.x;
    const int m0 = blockIdx.y * BM;
    const int n0 = blockIdx.x * BN;
    const int lane = tid & 63;
    const int w  = tid >> 6;         // 4 waves, 2x2 grid of 64x64 sub-tiles
    const int wm = (w >> 1) * 64;
    const int wn = (w & 1) * 64;
    const int r15 = lane & 15;
    const int kh  = lane >> 4;       // k-half group 0..3 (8 bf16 each)

    const int srow = tid >> 3;       // staging: 0..31
    const int c4   = tid & 7;        // float4 column within BK=32
    const int g    = c4 >> 1;        // k-group of 8
    const int hf   = c4 & 1;

    f4 ra[4], rb[4];
    f32x4 acc[4][4];
#pragma unroll
    for (int mi = 0; mi < 4; ++mi)
#pragma unroll
        for (int ni = 0; ni < 4; ++ni) {
            f32x4 z = {0.f, 0.f, 0.f, 0.f};
            acc[mi][ni] = z;
        }

#define LOAD_TILES(K0)                                                                   \
    {                                                                                    \
        _Pragma("unroll")                                                                \
        for (int p = 0; p < 4; ++p) {                                                    \
            int row = p * 32 + srow;                                                     \
            ra[p] = *reinterpret_cast<const f4*>(&x[(size_t)(m0 + row) * DACT + (K0) + c4 * 4]); \
            rb[p] = *reinterpret_cast<const f4*>(&W[(size_t)(n0 + row) * DACT + (K0) + c4 * 4]); \
        }                                                                                \
    }

    LOAD_TILES(0)

    for (int ks = 0; ks < DACT / BK; ++ks) {
        const int k0 = ks * BK;
        __syncthreads();
        // ---- split + write planes (swizzled: slot = g ^ (row&3) ^ ((row>>2)&3)) ----
        const f4 bd = *reinterpret_cast<const f4*>(&b_dec[k0 + c4 * 4]);
#pragma unroll
        for (int p = 0; p < 4; ++p) {
            int row = p * 32 + srow;
            int slot = (g ^ (row & 3) ^ ((row >> 2) & 3)) & 3;
            int base = row * BK + slot * 8 + hf * 4;
            us4 h1, l1, h2, l2;
#pragma unroll
            for (int j = 0; j < 4; ++j) {
                float va = ra[p][j] - bd[j];
                unsigned short ah = f2bf(va);
                float res = va - bf2f(ah);       // exact residual
                h1[j] = ah; l1[j] = f2bf(res);
                float vb = rb[p][j];
                unsigned short bh = f2bf(vb);
                float resb = vb - bf2f(bh);
                h2[j] = bh; l2[j] = f2bf(resb);
            }
            *reinterpret_cast<us4*>(&sA1[base]) = h1;
            *reinterpret_cast<us4*>(&sA2[base]) = l1;
            *reinterpret_cast<us4*>(&sB1[base]) = h2;
            *reinterpret_cast<us4*>(&sB2[base]) = l2;
        }
        if (ks + 1 < DACT / BK) LOAD_TILES(k0 + BK)   // issue next loads; latency hides under MFMA
        __syncthreads();
        // ---- fragments + 48 MFMA ----
        frag a1[4], a2[4];
#pragma unroll
        for (int mi = 0; mi < 4; ++mi) {
            int row = wm + mi * 16 + r15;
            int slot = (kh ^ (row & 3) ^ ((row >> 2) & 3)) & 3;
            int idx = row * BK + slot * 8;
            a1[mi] = *reinterpret_cast<const frag*>(&sA1[idx]);
            a2[mi] = *reinterpret_cast<const frag*>(&sA2[idx]);
        }
#pragma unroll
        for (int ni = 0; ni < 4; ++ni) {
            int row = wn + ni * 16 + r15;
            int slot = (kh ^ (row & 3) ^ ((row >> 2) & 3)) & 3;
            int idx = row * BK + slot * 8;
            frag b1 = *reinterpret_cast<const frag*>(&sB1[idx]);
            frag b2 = *reinterpret_cast<const frag*>(&sB2[idx]);
#pragma unroll
            for (int mi = 0; mi < 4; ++mi) {
                acc[mi][ni] = __builtin_amdgcn_mfma_f32_16x16x32_bf16(a1[mi], b1, acc[mi][ni], 0, 0, 0);
                acc[mi][ni] = __builtin_amdgcn_mfma_f32_16x16x32_bf16(a1[mi], b2, acc[mi][ni], 0, 0, 0);
                acc[mi][ni] = __builtin_amdgcn_mfma_f32_16x16x32_bf16(a2[mi], b1, acc[mi][ni], 0, 0, 0);
            }
        }
    }

    // ---- epilogue: +b_enc, relu, store f32 (C/D map: col=lane&15, row=(lane>>4)*4+q) ----
#pragma unroll
    for (int ni = 0; ni < 4; ++ni) {
        int n = n0 + wn + ni * 16 + r15;
        float be = b_enc[n];
#pragma unroll
        for (int mi = 0; mi < 4; ++mi) {
#pragma unroll
            for (int q = 0; q < 4; ++q) {
                int m = m0 + wm + mi * 16 + kh * 4 + q;
                float v = acc[mi][ni][q] + be;
                out[(size_t)m * DDICT + n] = v > 0.f ? v : 0.f;
            }
        }
    }
#undef LOAD_TILES
}

// ---------------- radix histogram passes (positive-float bit order) ----------------
__global__ __launch_bounds__(256) void hist_kernel(
    const float* __restrict__ acts, uint32_t* __restrict__ hist,
    const uint32_t* __restrict__ prefix_ptr, int prefix_shift,
    int bucket_shift, uint32_t mask)
{
    __shared__ uint32_t h[2048];
    for (int i = threadIdx.x; i < 2048; i += blockDim.x) h[i] = 0;
    __syncthreads();
    const uint32_t pref = prefix_ptr ? *prefix_ptr : 0;
    const bool has_pref = (prefix_ptr != nullptr);
    const size_t stride = (size_t)gridDim.x * blockDim.x;
    for (size_t i = (size_t)blockIdx.x * blockDim.x + threadIdx.x; i < NTOT; i += stride) {
        uint32_t bits = __float_as_uint(acts[i]);
        if (has_pref && (bits >> prefix_shift) != pref) continue;
        atomicAdd(&h[(bits >> bucket_shift) & mask], 1u);
    }
    __syncthreads();
    for (int i = threadIdx.x; i < 2048; i += blockDim.x)
        if (h[i]) atomicAdd(&hist[i], h[i]);
}

// single-wave suffix scan. state: [0]=b0, [1]=rem1, [2]=prefix22, [3]=rem2, [7]=T_lo bits, [8]=T_hi bits
__global__ void scan_kernel(const uint32_t* __restrict__ hist, int nbuckets,
                            const int* __restrict__ kptr, uint32_t* __restrict__ state, int mode)
{
    const int lane = threadIdx.x;   // 64 threads
    uint32_t rem = (mode == 0) ? (uint32_t)(*kptr) * (uint32_t)B_ROWS : state[1];

    const int seg = nbuckets >> 6;
    const int base = lane * seg;
    uint32_t s = 0;
    for (int j = 0; j < seg; ++j) s += hist[base + j];

    uint32_t suf = s;
    for (int off = 1; off < 64; off <<= 1) {
        uint32_t o = __shfl_down(suf, off);
        if (lane + off < 64) suf += o;
    }
    uint32_t snext = __shfl_down(suf, 1);
    if (lane == 63) snext = 0;

    if (suf >= rem && snext < rem) {
        uint32_t cum = snext;
        int bstar = base;
        for (int b = base + seg - 1; b >= base; --b) {
            cum += hist[b];
            if (cum >= rem) { bstar = b; break; }
        }
        uint32_t greater = cum - hist[bstar];
        uint32_t inner = rem - greater;
        if (mode == 0) { state[0] = (uint32_t)bstar; state[1] = inner; }
        else {
            state[2] = (state[0] << 11) | (uint32_t)bstar;
            state[3] = inner;
            uint32_t tb = state[2] << 10;            // lower edge of 22-bit bucket
            float t = __uint_as_float(tb);
            float lo = t - BETA; if (!(lo > 0.f)) lo = 0.f;
            float hi = t + BETA;
            state[7] = __float_as_uint(lo);
            state[8] = __float_as_uint(hi);
        }
    }
}

// count elements above band (cnt[0]) and gather band member indices (cnt[1], bidx)
__global__ __launch_bounds__(256) void band_gather(
    const float* __restrict__ acts, const uint32_t* __restrict__ state,
    uint32_t* __restrict__ cnt, uint32_t* __restrict__ bidx)
{
    __shared__ uint32_t s_hi;
    if (threadIdx.x == 0) s_hi = 0;
    __syncthreads();
    const uint32_t Tl = state[7], Th = state[8];
    const size_t stride = (size_t)gridDim.x * blockDim.x;
    const uint4* a4 = reinterpret_cast<const uint4*>(acts);
    uint32_t local_hi = 0;
    for (size_t i = (size_t)blockIdx.x * blockDim.x + threadIdx.x; i < NTOT / 4; i += stride) {
        uint4 v = a4[i];
        uint32_t b;
        b = v.x; if (b > Th) local_hi++; else if (b >= Tl) { uint32_t p = atomicAdd(&cnt[1], 1u); if (p < CAP) bidx[p] = (uint32_t)(i * 4 + 0); }
        b = v.y; if (b > Th) local_hi++; else if (b >= Tl) { uint32_t p = atomicAdd(&cnt[1], 1u); if (p < CAP) bidx[p] = (uint32_t)(i * 4 + 1); }
        b = v.z; if (b > Th) local_hi++; else if (b >= Tl) { uint32_t p = atomicAdd(&cnt[1], 1u); if (p < CAP) bidx[p] = (uint32_t)(i * 4 + 2); }
        b = v.w; if (b > Th) local_hi++; else if (b >= Tl) { uint32_t p = atomicAdd(&cnt[1], 1u); if (p < CAP) bidx[p] = (uint32_t)(i * 4 + 3); }
    }
    if (local_hi) atomicAdd(&s_hi, local_hi);
    __syncthreads();
    if (threadIdx.x == 0 && s_hi) atomicAdd(&cnt[0], s_hi);
}

// exact f64 recomputation of each band element
__global__ __launch_bounds__(256) void eqval_kernel(
    const float* __restrict__ x, const float* __restrict__ W,
    const float* __restrict__ b_enc, const float* __restrict__ b_dec,
    const uint32_t* __restrict__ cnt, const uint32_t* __restrict__ bidx,
    double* __restrict__ eval)
{
    __shared__ double red[256];
    uint32_t n = cnt[1]; if (n > CAP) n = CAP;
    if (blockIdx.x >= n) return;
    const uint32_t idx = bidx[blockIdx.x];
    const int brow = (int)(idx >> 15);       // DDICT = 2^15
    const int f = (int)(idx & 32767u);
    double s = 0.0;
    for (int d = threadIdx.x; d < DACT; d += 256)
        s = fma((double)x[(size_t)brow * DACT + d] - (double)b_dec[d],
                (double)W[(size_t)f * DACT + d], s);
    red[threadIdx.x] = s;
    __syncthreads();
    for (int off = 128; off > 0; off >>= 1) {
        if (threadIdx.x < off) red[threadIdx.x] += red[threadIdx.x + off];
        __syncthreads();
    }
    if (threadIdx.x == 0) eval[blockIdx.x] = red[0] + (double)b_enc[f];
}

// zero everything <= T_hi (band included; chosen band elements rewritten by band_rank)
__global__ __launch_bounds__(256) void finalize_kernel(
    float* __restrict__ out, const uint32_t* __restrict__ state)
{
    const uint32_t Th = state[8];
    const size_t stride = (size_t)gridDim.x * blockDim.x;
    uint4* o4 = reinterpret_cast<uint4*>(out);
    for (size_t i = (size_t)blockIdx.x * blockDim.x + threadIdx.x; i < NTOT / 4; i += stride) {
        uint4 v = o4[i];
        if (v.x <= Th) v.x = 0u;
        if (v.y <= Th) v.y = 0u;
        if (v.z <= Th) v.z = 0u;
        if (v.w <= Th) v.w = 0u;
        o4[i] = v;
    }
}

// among band elements pick top-r by (exact value desc, index asc), write exact values
__global__ void band_rank(float* __restrict__ out, const int* __restrict__ kptr,
                          const uint32_t* __restrict__ cnt,
                          const uint32_t* __restrict__ bidx,
                          const double* __restrict__ eval)
{
    uint32_t n = cnt[1]; if (n > CAP) n = CAP;
    const uint32_t chi = cnt[0];
    const uint32_t Ktot = (uint32_t)(*kptr) * (uint32_t)B_ROWS;
    int r = (int)Ktot - (int)chi;
    if (r < 0) r = 0;
    if ((uint32_t)r > n) r = (int)n;
    const size_t stride = (size_t)gridDim.x * blockDim.x;
    for (uint32_t i = (uint32_t)(blockIdx.x * blockDim.x + threadIdx.x); i < n; i += (uint32_t)stride) {
        const double v = eval[i];
        const uint32_t idx = bidx[i];
        uint32_t rank = 0;
        for (uint32_t j = 0; j < n; ++j) {
            double vj = eval[j];
            if (vj > v || (vj == v && bidx[j] < idx)) rank++;
        }
        if (rank < (uint32_t)r) out[idx] = (float)v;
    }
}

extern "C" void kernel_launch(void* const* d_in, const int* in_sizes, int n_in,
                              void* d_out, int out_size, void* d_ws, size_t ws_size,
                              hipStream_t stream)
{
    const float* x     = (const float*)d_in[0];
    const float* W     = (const float*)d_in[1];
    const float* b_enc = (const float*)d_in[2];
    const float* b_dec = (const float*)d_in[3];
    const int*   kp    = (const int*)d_in[4];
    float* out = (float*)d_out;

    // ws layout (u32 offsets): hist0[0..2048), hist1[2048..4096), state[4096..4112),
    // cnt[4112..4114), bidx[4128..4128+CAP), eval(f64) at u32 offset 4128+CAP (8B aligned)
    uint32_t* ws    = (uint32_t*)d_ws;
    uint32_t* hist0 = ws;
    uint32_t* hist1 = ws + 2048;
    uint32_t* state = ws + 4096;
    uint32_t* cnt   = ws + 4112;
    uint32_t* bidx  = ws + 4128;
    double*   eval  = (double*)(ws + 4128 + CAP);   // (4128+8192)*4 = 49280, /8 ok

    hipMemsetAsync(d_ws, 0, (size_t)4128 * sizeof(uint32_t), stream);

    gemm_kernel<<<dim3(DDICT / BN, B_ROWS / BM), 256, 0, stream>>>(x, W, b_enc, b_dec, out);

    hist_kernel<<<4096, 256, 0, stream>>>(out, hist0, nullptr, 0, 21, 0x7FFu);
    scan_kernel<<<1, 64, 0, stream>>>(hist0, 2048, kp, state, 0);
    hist_kernel<<<4096, 256, 0, stream>>>(out, hist1, state + 0, 21, 10, 0x7FFu);
    scan_kernel<<<1, 64, 0, stream>>>(hist1, 2048, kp, state, 1);

    band_gather<<<4096, 256, 0, stream>>>(out, state, cnt, bidx);
    eqval_kernel<<<CAP, 256, 0, stream>>>(x, W, b_enc, b_dec, cnt, bidx, eval);
    finalize_kernel<<<4096, 256, 0, stream>>>(out, state);
    band_rank<<<32, 256, 0, stream>>>(out, kp, cnt, bidx, eval);
}